// Round 2
// baseline (4239.031 us; speedup 1.0000x reference)
//
#include <hip/hip_runtime.h>
#include <hip/hip_bf16.h>
#include <hip/hip_cooperative_groups.h>
#include <stdint.h>

namespace cg = cooperative_groups;

typedef unsigned short ushort_t;

#define HID 512
#define FOURH 2048
#define BSZ 32
#define SLEN 50
#define TDEC 39
#define EMB 256
#define VOC 32000

using short8  = __attribute__((ext_vector_type(8))) short;
using float4v = __attribute__((ext_vector_type(4))) float;

__device__ inline float bf16lo(uint32_t u) { return __uint_as_float(u << 16); }
__device__ inline float bf16hi(uint32_t u) { return __uint_as_float(u & 0xffff0000u); }

__device__ inline ushort_t f32_to_bf16(float f) {
    uint32_t u = __float_as_uint(f);
    uint32_t r = (u + 0x7fffu + ((u >> 16) & 1u)) >> 16;
    return (ushort_t)r;
}

__device__ inline float sigmoid_f(float x) { return 1.0f / (1.0f + expf(-x)); }

// ---------------------------------------------------------------------------
// Runtime dtype detection. Probe = enc_b0 (values ~N(0,1)*0.05).
// Returns 1 if inputs are fp32 (wave-uniform).
// ---------------------------------------------------------------------------
__device__ inline int detect_f32(const ushort_t* __restrict__ probe) {
    int cnt = 0;
#pragma unroll
    for (int i = 0; i < 64; ++i) {
        int e = (probe[i] >> 7) & 0xFF;
        cnt += (e >= 0x8A);
    }
    return cnt > 0;
}

// ---------------------------------------------------------------------------
// Embedding gather -> bf16 pairs. Handles bf16 or fp32 source table.
// ---------------------------------------------------------------------------
__global__ void embed_kernel(const int* __restrict__ idx,
                             const void* __restrict__ emb,
                             uint32_t* __restrict__ out,
                             int total_u,
                             const ushort_t* __restrict__ probe)
{
    const int F32 = detect_f32(probe);
    int i = blockIdx.x * 256 + threadIdx.x;
    if (i >= total_u) return;
    int tok = i >> 7;          // EMB/2 = 128 uints per row
    int col = i & 127;
    int row = idx[tok];
    if (F32) {
        const float* ef = (const float*)emb + (size_t)row * EMB + col * 2;
        uint32_t lo = f32_to_bf16(ef[0]);
        uint32_t hi = f32_to_bf16(ef[1]);
        out[i] = lo | (hi << 16);
    } else {
        out[i] = ((const uint32_t*)emb)[(size_t)row * 128 + col];
    }
}

__device__ inline float load_bias(const void* __restrict__ bias, int n, int F32) {
    if (F32) return ((const float*)bias)[n];
    return __uint_as_float(((uint32_t)((const ushort_t*)bias)[n]) << 16);
}

__device__ inline void gload_lds16(const ushort_t* __restrict__ g, ushort_t* l) {
    __builtin_amdgcn_global_load_lds(
        (const __attribute__((address_space(1))) uint32_t*)g,
        (__attribute__((address_space(3))) uint32_t*)l,
        16, 0, 0);
}

// ---------------------------------------------------------------------------
// Tiled GEMM: C[M,N] = A[M,K](bf16 internal) @ W[N,K](bf16|fp32)^T + bias
// 128x128 tile, BK=64, 4 waves (2x2), XOR-swizzled LDS (see round-1 notes).
// SMODE 0: C = float* scratch; SMODE 1: C = d_out, idx=(32+m)*N+n.
// ---------------------------------------------------------------------------
template <int SMODE>
__global__ __launch_bounds__(256, 2)
void gemm_tile_kernel(const ushort_t* __restrict__ A,
                      const void* __restrict__ W,
                      const void* __restrict__ bias,
                      void* __restrict__ C,
                      int M, int N, int K,
                      const ushort_t* __restrict__ probe)
{
    const int F32 = detect_f32(probe);
    __shared__ ushort_t Alds[128 * 64];   // 16 KB
    __shared__ ushort_t Blds[128 * 64];   // 16 KB

    const int tid  = threadIdx.x;
    const int lane = tid & 63;
    const int wave = tid >> 6;
    const int l16  = lane & 15;
    const int l4   = lane >> 4;

    const int wm = (wave >> 1) * 64;
    const int wn = (wave & 1) * 64;

    const int mbase = blockIdx.x * 128;
    const int nbase = blockIdx.y * 128;

    const int sr   = lane >> 3;                   // sub-row 0..7
    const int scol = ((lane & 7) ^ sr) * 8;       // swizzled source col (elems)

    float4v acc[4][4];
#pragma unroll
    for (int i = 0; i < 4; ++i)
#pragma unroll
        for (int j = 0; j < 4; ++j) acc[i][j] = (float4v){0.f, 0.f, 0.f, 0.f};

    for (int k0 = 0; k0 < K; k0 += 64) {
        __syncthreads();

#pragma unroll
        for (int c = 0; c < 4; ++c) {
            int chunk = wave * 4 + c;
            int row   = chunk * 8 + sr;
            gload_lds16(A + (size_t)(mbase + row) * K + k0 + scol,
                        Alds + chunk * 512);
        }
        if (F32) {
#pragma unroll
            for (int c = 0; c < 4; ++c) {
                int chunk = wave * 4 + c;
                int row   = chunk * 8 + sr;
                const float* gp = (const float*)W + (size_t)(nbase + row) * K + k0 + scol;
                float4v f0 = *(const float4v*)gp;
                float4v f1 = *(const float4v*)(gp + 4);
                short8 v;
#pragma unroll
                for (int j = 0; j < 4; ++j) v[j]     = (short)f32_to_bf16(f0[j]);
#pragma unroll
                for (int j = 0; j < 4; ++j) v[4 + j] = (short)f32_to_bf16(f1[j]);
                *(short8*)(Blds + chunk * 512 + lane * 8) = v;
            }
        } else {
#pragma unroll
            for (int c = 0; c < 4; ++c) {
                int chunk = wave * 4 + c;
                int row   = chunk * 8 + sr;
                gload_lds16((const ushort_t*)W + (size_t)(nbase + row) * K + k0 + scol,
                            Blds + chunk * 512);
            }
        }
        __syncthreads();

        short8 af[4][2], bf[4][2];
#pragma unroll
        for (int mi = 0; mi < 4; ++mi) {
            int row = wm + mi * 16 + l16;
#pragma unroll
            for (int kk = 0; kk < 2; ++kk) {
                int cb = (kk * 64 + l4 * 16) ^ ((l16 & 7) << 4);
                af[mi][kk] = *(const short8*)((const char*)Alds + row * 128 + cb);
            }
        }
#pragma unroll
        for (int ni = 0; ni < 4; ++ni) {
            int row = wn + ni * 16 + l16;
#pragma unroll
            for (int kk = 0; kk < 2; ++kk) {
                int cb = (kk * 64 + l4 * 16) ^ ((l16 & 7) << 4);
                bf[ni][kk] = *(const short8*)((const char*)Blds + row * 128 + cb);
            }
        }
#pragma unroll
        for (int mi = 0; mi < 4; ++mi)
#pragma unroll
            for (int ni = 0; ni < 4; ++ni) {
                acc[mi][ni] = __builtin_amdgcn_mfma_f32_16x16x32_bf16(
                    af[mi][0], bf[ni][0], acc[mi][ni], 0, 0, 0);
                acc[mi][ni] = __builtin_amdgcn_mfma_f32_16x16x32_bf16(
                    af[mi][1], bf[ni][1], acc[mi][ni], 0, 0, 0);
            }
    }

#pragma unroll
    for (int mi = 0; mi < 4; ++mi) {
#pragma unroll
        for (int ni = 0; ni < 4; ++ni) {
            int n = nbase + wn + ni * 16 + l16;
            float bv = load_bias(bias, n, F32);
#pragma unroll
            for (int r = 0; r < 4; ++r) {
                int m = mbase + wm + mi * 16 + l4 * 4 + r;
                if (m < M) {
                    float v = acc[mi][ni][r] + bv;
                    if (SMODE == 0) {
                        ((float*)C)[(size_t)m * N + n] = v;
                    } else {
                        size_t idx = (size_t)(BSZ + m) * N + n;
                        if (F32) ((float*)C)[idx] = v;
                        else     ((ushort_t*)C)[idx] = f32_to_bf16(v);
                    }
                }
            }
        }
    }
}

// ---------------------------------------------------------------------------
// PERSISTENT LSTM layer: one cooperative launch runs all T timesteps.
// Grid 64 WGs x 256 threads. WG owns 8 hidden units (j0 = wg*8):
//   32 Whh rows ordered rr = u8*4 + gate (u8 0..7, gate 0..3 = i,f,g,o)
//   -> all 4 gates of a unit land in 4 ADJACENT lanes of the MFMA output.
// Whh slice staged to LDS once (bf16, XOR-swizzled). Cell state in regs.
// Per step: stage h (32x512 bf16, global->LDS), 16 MFMA/wave (M=32 batch,
// N=32 rows, K=512), gate gather via __shfl, cell update, h write, grid sync.
// h double-buffered in global by parity (t&1 read, (t+1)&1 write).
// ---------------------------------------------------------------------------
__global__ __launch_bounds__(256, 1)
void lstm_layer_kernel(const float* __restrict__ xih,   // (T,32,2048) fp32
                       ushort_t* __restrict__ hbuf,     // 2 x (32,512) bf16
                       float*    __restrict__ cbuf,     // (32,512) fp32
                       const void* __restrict__ Whh,    // (2048,512) bf16|fp32
                       ushort_t* __restrict__ ys,       // (T,32,512) bf16 | null
                       const ushort_t* __restrict__ probe,
                       int T)
{
    const int F32 = detect_f32(probe);
    cg::grid_group grid = cg::this_grid();

    __shared__ ushort_t w_lds[32 * 512];   // 32 KB
    __shared__ ushort_t h_lds[32 * 512];   // 32 KB

    const int tid  = threadIdx.x;
    const int lane = tid & 63;
    const int wave = tid >> 6;
    const int l16  = lane & 15;
    const int quad = lane >> 4;
    const int j0   = blockIdx.x * 8;

    const int m0 = (wave >> 1) * 16;        // batch half
    const int ni = wave & 1;                // unit-quad select (rows ni*16..+16)

    // ---- stage Whh slice once (rows rr -> Whh row gate*HID + j0 + u8)
#pragma unroll
    for (int i = 0; i < 8; ++i) {
        int idx = tid + i * 256;            // 0..2047 16B-chunks
        int rr  = idx >> 6;
        int c16 = idx & 63;
        int gate = rr & 3, u8 = rr >> 2;
        size_t grow = (size_t)(gate * HID + j0 + u8) * HID + c16 * 8;
        short8 v;
        if (F32) {
            const float* gp = (const float*)Whh + grow;
            float4v f0 = *(const float4v*)gp;
            float4v f1 = *(const float4v*)(gp + 4);
#pragma unroll
            for (int j = 0; j < 4; ++j) v[j]     = (short)f32_to_bf16(f0[j]);
#pragma unroll
            for (int j = 0; j < 4; ++j) v[4 + j] = (short)f32_to_bf16(f1[j]);
        } else {
            v = *(const short8*)((const ushort_t*)Whh + grow);
        }
        *(short8*)((char*)w_lds + rr * 1024 + ((c16 * 16) ^ ((rr & 7) << 4))) = v;
    }

    // ---- lane's (unit, gate) identity in the MFMA output tile
    const int u8me = ni * 4 + (l16 >> 2);
    const int gme  = l16 & 3;
    const int jme  = j0 + u8me;

    // cell state in registers (maintained by gate-0 lanes)
    float creg[4];
#pragma unroll
    for (int r = 0; r < 4; ++r)
        creg[r] = cbuf[(m0 + quad * 4 + r) * HID + jme];

    const bool has_ys = (ys != nullptr);

    for (int t = 0; t < T; ++t) {
        const ushort_t* hin  = hbuf + (size_t)(t & 1) * (BSZ * HID);
        ushort_t*       hout = hbuf + (size_t)((t + 1) & 1) * (BSZ * HID);
        const float*    xr   = xih + (size_t)t * (BSZ * FOURH);

        // prefetch this step's xih slice (overlaps with staging/barrier)
        float xv[4];
#pragma unroll
        for (int r = 0; r < 4; ++r)
            xv[r] = xr[(m0 + quad * 4 + r) * FOURH + gme * HID + jme];

        // stage h -> LDS (swizzled)
#pragma unroll
        for (int i = 0; i < 8; ++i) {
            int idx = tid + i * 256;
            int b   = idx >> 6;
            int c16 = idx & 63;
            short8 v = *(const short8*)(hin + (size_t)b * HID + c16 * 8);
            *(short8*)((char*)h_lds + b * 1024 + ((c16 * 16) ^ ((b & 7) << 4))) = v;
        }
        __syncthreads();

        // MFMA: 16x16 output tile per wave (batch-half x row-half), K=512
        float4v acc = (float4v){0.f, 0.f, 0.f, 0.f};
#pragma unroll
        for (int kk = 0; kk < 16; ++kk) {
            int cb = (kk * 64 + quad * 16) ^ ((l16 & 7) << 4);
            short8 a = *(const short8*)((const char*)h_lds + (m0 + l16) * 1024 + cb);
            short8 b = *(const short8*)((const char*)w_lds + (ni * 16 + l16) * 1024 + cb);
            acc = __builtin_amdgcn_mfma_f32_16x16x32_bf16(a, b, acc, 0, 0, 0);
        }

        // gates: activation first (uniform single expf), then gather via shfl
#pragma unroll
        for (int r = 0; r < 4; ++r) {
            float g   = acc[r] + xv[r];
            // gate 2 needs tanh(g) = 2*sig(2g)-1; others sigmoid(g)
            float arg = (gme == 2) ? 2.f * g : g;
            float s   = 1.f / (1.f + expf(-arg));
            float act = (gme == 2) ? 2.f * s - 1.f : s;
            int base = lane & ~3;
            float ai = __shfl(act, base + 0);
            float af = __shfl(act, base + 1);
            float ag = __shfl(act, base + 2);
            float ao = __shfl(act, base + 3);
            if (gme == 0) {
                float cn = af * creg[r] + ai * ag;
                creg[r] = cn;
                float th = 2.f / (1.f + expf(-2.f * cn)) - 1.f;   // tanh(cn)
                float hn = ao * th;
                ushort_t hb = f32_to_bf16(hn);
                int b = m0 + quad * 4 + r;
                hout[b * HID + jme] = hb;
                if (has_ys) ys[(size_t)t * (BSZ * HID) + b * HID + jme] = hb;
            }
        }

        __syncthreads();        // h_lds reuse guard
        __threadfence();        // release h writes (agent scope)
        grid.sync();
        __threadfence();        // acquire: invalidate L1 before next h read
    }

    // final cell state (needed when a decoder layer continues this state)
    if (gme == 0) {
#pragma unroll
        for (int r = 0; r < 4; ++r)
            cbuf[(m0 + quad * 4 + r) * HID + jme] = creg[r];
    }
}

// ---------------------------------------------------------------------------
// Fallback per-step LSTM kernel (used only if cooperative launch fails).
// ---------------------------------------------------------------------------
__global__ void lstm_step_kernel(const float* __restrict__ xih,
                                 const ushort_t* __restrict__ h_in,
                                 ushort_t* __restrict__ h_out,
                                 float* __restrict__ c,
                                 const void* __restrict__ Whh,
                                 ushort_t* __restrict__ ys,
                                 const ushort_t* __restrict__ probe)
{
    const int F32 = detect_f32(probe);
    __shared__ uint32_t h_lds[BSZ * 257];
    __shared__ uint32_t w_lds[8 * 256];
    __shared__ float    g_lds[8][BSZ];

    const int tid = threadIdx.x;
    const int j0  = blockIdx.x * 2;

    const uint32_t* h32 = (const uint32_t*)h_in;
#pragma unroll
    for (int i = 0; i < 32; ++i) {
        int idx = tid + i * 256;
        int row = idx >> 8, col = idx & 255;
        h_lds[row * 257 + col] = h32[idx];
    }
#pragma unroll
    for (int i = 0; i < 8; ++i) {
        int idx  = tid + i * 256;
        int lrr  = idx >> 8, col = idx & 255;
        int gate = lrr >> 1, jl = lrr & 1;
        size_t wrow = (size_t)(gate * HID + j0 + jl);
        if (F32) {
            const float* wf = (const float*)Whh + wrow * HID + col * 2;
            uint32_t lo = f32_to_bf16(wf[0]);
            uint32_t hi = f32_to_bf16(wf[1]);
            w_lds[lrr * 256 + col] = lo | (hi << 16);
        } else {
            w_lds[lrr * 256 + col] = ((const uint32_t*)Whh)[wrow * 256 + col];
        }
    }
    __syncthreads();

    const int b    = tid & 31;
    const int lr   = tid >> 5;
    const int gate = lr >> 1;
    const int jl   = lr & 1;

    float dot = xih[b * FOURH + gate * HID + j0 + jl];
    const uint32_t* hr = &h_lds[b * 257];
    const uint32_t* wr = &w_lds[lr * 256];
    float s0 = 0.f, s1 = 0.f;
#pragma unroll 8
    for (int k = 0; k < 256; ++k) {
        uint32_t hu = hr[k], wu = wr[k];
        s0 += bf16lo(hu) * bf16lo(wu);
        s1 += bf16hi(hu) * bf16hi(wu);
    }
    g_lds[lr][b] = dot + s0 + s1;
    __syncthreads();

    if (tid < 64) {
        int b2 = tid & 31, jl2 = tid >> 5;
        int j  = j0 + jl2;
        float gi = g_lds[(0 << 1) | jl2][b2];
        float gf = g_lds[(1 << 1) | jl2][b2];
        float gg = g_lds[(2 << 1) | jl2][b2];
        float go = g_lds[(3 << 1) | jl2][b2];
        float cold = c[b2 * HID + j];
        float cn = sigmoid_f(gf) * cold + sigmoid_f(gi) * tanhf(gg);
        float hn = sigmoid_f(go) * tanhf(cn);
        c[b2 * HID + j] = cn;
        ushort_t hb = f32_to_bf16(hn);
        h_out[b2 * HID + j] = hb;
        if (ys) ys[b2 * HID + j] = hb;
    }
}

// ---------------------------------------------------------------------------
// Zero the first output timestep (elements [0, 32*VOC)), dtype per mode.
// ---------------------------------------------------------------------------
__global__ void zero_row_kernel(void* __restrict__ outv,
                                const ushort_t* __restrict__ probe)
{
    const int F32 = detect_f32(probe);
    int i = blockIdx.x * 256 + threadIdx.x;
    if (i >= BSZ * VOC) return;
    if (F32) ((uint32_t*)outv)[i] = 0u;
    else     ((ushort_t*)outv)[i] = 0;
}

// ---------------------------------------------------------------------------
// Scratch layout inside d_out (unchanged from round 1):
//   dy1 (bf16) at byte 0; arena at 4 MiB; all arena dead before projection.
// ---------------------------------------------------------------------------
extern "C" void kernel_launch(void* const* d_in, const int* in_sizes, int n_in,
                              void* d_out, int out_size, void* d_ws, size_t ws_size,
                              hipStream_t stream)
{
    const int*      src      = (const int*)d_in[0];
    const int*      trg      = (const int*)d_in[1];
    const void*     enc_emb  = d_in[2];
    const void*     enc_Wih0 = d_in[3];
    const void*     enc_Whh0 = d_in[4];
    const void*     enc_b0   = d_in[5];
    const void*     enc_Wih1 = d_in[6];
    const void*     enc_Whh1 = d_in[7];
    const void*     enc_b1   = d_in[8];
    const void*     dec_emb  = d_in[9];
    const void*     dec_Wih0 = d_in[10];
    const void*     dec_Whh0 = d_in[11];
    const void*     dec_b0   = d_in[12];
    const void*     dec_Wih1 = d_in[13];
    const void*     dec_Whh1 = d_in[14];
    const void*     dec_b1   = d_in[15];
    const void*     out_W    = d_in[16];
    const void*     out_b    = d_in[17];

    const ushort_t* probe = (const ushort_t*)enc_b0;

    const int ME = SLEN * BSZ;   // 1600
    const int MD = TDEC * BSZ;   // 1248

    ushort_t* dy1 = (ushort_t*)d_out;

    char*  arena = (char*)d_out + (4u << 20);
    size_t aoff  = 0;
    auto acarve = [&](size_t bytes) -> void* {
        void* p = arena + aoff;
        aoff = (aoff + bytes + 255) & ~(size_t)255;
        return p;
    };
    const size_t HSTATE = (size_t)BSZ * HID;                       // 16384 elems
    float*    Xbig = (float*)acarve((size_t)ME * FOURH * 4);       // 13.1 MB
    ushort_t* X0   = (ushort_t*)acarve((size_t)ME * EMB * 2);
    ushort_t* DX0  = (ushort_t*)acarve((size_t)MD * EMB * 2);
    ushort_t* ys0  = (ushort_t*)acarve((size_t)ME * HID * 2);
    ushort_t* dy0  = (ushort_t*)acarve((size_t)MD * HID * 2);
    ushort_t* h0b  = (ushort_t*)acarve(2 * HSTATE * 2);
    float*    c0b  = (float*)acarve(HSTATE * 4);
    ushort_t* h1b  = (ushort_t*)acarve(2 * HSTATE * 2);
    float*    c1b  = (float*)acarve(HSTATE * 4);

    hipMemsetAsync(h0b, 0, HSTATE * 2, stream);
    hipMemsetAsync(c0b, 0, HSTATE * 4, stream);
    hipMemsetAsync(h1b, 0, HSTATE * 2, stream);
    hipMemsetAsync(c1b, 0, HSTATE * 4, stream);

    {
        int tu = ME * (EMB / 2);
        embed_kernel<<<(tu + 255) / 256, 256, 0, stream>>>(
            src, enc_emb, (uint32_t*)X0, tu, probe);
        int td = MD * (EMB / 2);
        embed_kernel<<<(td + 255) / 256, 256, 0, stream>>>(
            trg, dec_emb, (uint32_t*)DX0, td, probe);
    }

    const size_t XIH_T = (size_t)BSZ * FOURH;
    const int MTE = (ME + 127) / 128;
    const int MTD = (MD + 127) / 128;

    // persistent LSTM layer launcher (cooperative; per-step fallback on error)
    auto launch_lstm = [&](const float* xih, ushort_t* hb, float* cb,
                           const void* Whh, ushort_t* ysp, int T) {
        const float* a0 = xih; ushort_t* a1 = hb; float* a2 = cb;
        const void* a3 = Whh; ushort_t* a4 = ysp;
        const ushort_t* a5 = probe; int a6 = T;
        void* ka[] = {(void*)&a0, (void*)&a1, (void*)&a2, (void*)&a3,
                      (void*)&a4, (void*)&a5, (void*)&a6};
        hipError_t e = hipLaunchCooperativeKernel(
            reinterpret_cast<const void*>(&lstm_layer_kernel),
            dim3(64), dim3(256), ka, 0, stream);
        if (e != hipSuccess) {
            for (int t = 0; t < T; ++t)
                lstm_step_kernel<<<256, 256, 0, stream>>>(
                    xih + (size_t)t * XIH_T,
                    hb + (t & 1) * HSTATE, hb + ((t + 1) & 1) * HSTATE,
                    cb, Whh,
                    ysp ? ysp + (size_t)t * HSTATE : (ushort_t*)nullptr,
                    probe);
        }
    };

    // encoder layer 0
    gemm_tile_kernel<0><<<dim3(MTE, FOURH / 128), 256, 0, stream>>>(
        X0, enc_Wih0, enc_b0, Xbig, ME, FOURH, EMB, probe);
    launch_lstm(Xbig, h0b, c0b, enc_Whh0, ys0, SLEN);

    // encoder layer 1 (only final state needed)
    gemm_tile_kernel<0><<<dim3(MTE, FOURH / 128), 256, 0, stream>>>(
        ys0, enc_Wih1, enc_b1, Xbig, ME, FOURH, HID, probe);
    launch_lstm(Xbig, h1b, c1b, enc_Whh1, (ushort_t*)nullptr, SLEN);
    // 50 steps (even): final h at parity 0 -> decoder t=0 reads parity 0.

    // decoder layer 0 (continues h0b/c0b)
    gemm_tile_kernel<0><<<dim3(MTD, FOURH / 128), 256, 0, stream>>>(
        DX0, dec_Wih0, dec_b0, Xbig, MD, FOURH, EMB, probe);
    launch_lstm(Xbig, h0b, c0b, dec_Whh0, dy0, TDEC);

    // decoder layer 1 (continues h1b/c1b)
    gemm_tile_kernel<0><<<dim3(MTD, FOURH / 128), 256, 0, stream>>>(
        dy0, dec_Wih1, dec_b1, Xbig, MD, FOURH, HID, probe);
    launch_lstm(Xbig, h1b, c1b, dec_Whh1, dy1, TDEC);

    // projection: reads dy1 + out_W/out_b; writes [32*VOC, 1280*VOC) of d_out
    gemm_tile_kernel<1><<<dim3(MTD, VOC / 128), 256, 0, stream>>>(
        dy1, out_W, out_b, d_out, MD, VOC, HID, probe);

    // zero first output timestep — also wipes dy1
    zero_row_kernel<<<(BSZ * VOC + 255) / 256, 256, 0, stream>>>(d_out, probe);
}

// Round 3
// 1818.243 us; speedup vs baseline: 2.3314x; 2.3314x over previous
//
#include <hip/hip_runtime.h>
#include <hip/hip_bf16.h>
#include <stdint.h>

typedef unsigned short ushort_t;

#define HID 512
#define FOURH 2048
#define BSZ 32
#define SLEN 50
#define TDEC 39
#define EMB 256
#define VOC 32000
#define NWG_LSTM 64

using short8  = __attribute__((ext_vector_type(8))) short;
using float4v = __attribute__((ext_vector_type(4))) float;

__device__ inline float bf16lo(uint32_t u) { return __uint_as_float(u << 16); }
__device__ inline float bf16hi(uint32_t u) { return __uint_as_float(u & 0xffff0000u); }

__device__ inline ushort_t f32_to_bf16(float f) {
    uint32_t u = __float_as_uint(f);
    uint32_t r = (u + 0x7fffu + ((u >> 16) & 1u)) >> 16;
    return (ushort_t)r;
}

__device__ inline float sigmoid_f(float x) { return 1.0f / (1.0f + expf(-x)); }

// ---------------------------------------------------------------------------
// Runtime dtype detection. Probe = enc_b0 (values ~N(0,1)*0.05).
// Returns 1 if inputs are fp32 (wave-uniform).
// ---------------------------------------------------------------------------
__device__ inline int detect_f32(const ushort_t* __restrict__ probe) {
    int cnt = 0;
#pragma unroll
    for (int i = 0; i < 64; ++i) {
        int e = (probe[i] >> 7) & 0xFF;
        cnt += (e >= 0x8A);
    }
    return cnt > 0;
}

// ---------------------------------------------------------------------------
// Embedding gather -> bf16 pairs. Handles bf16 or fp32 source table.
// ---------------------------------------------------------------------------
__global__ void embed_kernel(const int* __restrict__ idx,
                             const void* __restrict__ emb,
                             uint32_t* __restrict__ out,
                             int total_u,
                             const ushort_t* __restrict__ probe)
{
    const int F32 = detect_f32(probe);
    int i = blockIdx.x * 256 + threadIdx.x;
    if (i >= total_u) return;
    int tok = i >> 7;          // EMB/2 = 128 uints per row
    int col = i & 127;
    int row = idx[tok];
    if (F32) {
        const float* ef = (const float*)emb + (size_t)row * EMB + col * 2;
        uint32_t lo = f32_to_bf16(ef[0]);
        uint32_t hi = f32_to_bf16(ef[1]);
        out[i] = lo | (hi << 16);
    } else {
        out[i] = ((const uint32_t*)emb)[(size_t)row * 128 + col];
    }
}

__device__ inline float load_bias(const void* __restrict__ bias, int n, int F32) {
    if (F32) return ((const float*)bias)[n];
    return __uint_as_float(((uint32_t)((const ushort_t*)bias)[n]) << 16);
}

__device__ inline void gload_lds16(const ushort_t* __restrict__ g, ushort_t* l) {
    __builtin_amdgcn_global_load_lds(
        (const __attribute__((address_space(1))) uint32_t*)g,
        (__attribute__((address_space(3))) uint32_t*)l,
        16, 0, 0);
}

// ---------------------------------------------------------------------------
// Tiled GEMM: C[M,N] = A[M,K](bf16 internal) @ W[N,K](bf16|fp32)^T + bias
// 128x128 tile, BK=64, 4 waves (2x2), XOR-swizzled LDS (see round-1 notes).
// SMODE 0: C = float* scratch; SMODE 1: C = d_out, idx=(32+m)*N+n.
// ---------------------------------------------------------------------------
template <int SMODE>
__global__ __launch_bounds__(256, 3)
void gemm_tile_kernel(const ushort_t* __restrict__ A,
                      const void* __restrict__ W,
                      const void* __restrict__ bias,
                      void* __restrict__ C,
                      int M, int N, int K,
                      const ushort_t* __restrict__ probe)
{
    const int F32 = detect_f32(probe);
    __shared__ ushort_t Alds[128 * 64];   // 16 KB
    __shared__ ushort_t Blds[128 * 64];   // 16 KB

    const int tid  = threadIdx.x;
    const int lane = tid & 63;
    const int wave = tid >> 6;
    const int l16  = lane & 15;
    const int l4   = lane >> 4;

    const int wm = (wave >> 1) * 64;
    const int wn = (wave & 1) * 64;

    const int mbase = blockIdx.x * 128;
    const int nbase = blockIdx.y * 128;

    const int sr   = lane >> 3;                   // sub-row 0..7
    const int scol = ((lane & 7) ^ sr) * 8;       // swizzled source col (elems)

    float4v acc[4][4];
#pragma unroll
    for (int i = 0; i < 4; ++i)
#pragma unroll
        for (int j = 0; j < 4; ++j) acc[i][j] = (float4v){0.f, 0.f, 0.f, 0.f};

    for (int k0 = 0; k0 < K; k0 += 64) {
        __syncthreads();

#pragma unroll
        for (int c = 0; c < 4; ++c) {
            int chunk = wave * 4 + c;
            int row   = chunk * 8 + sr;
            gload_lds16(A + (size_t)(mbase + row) * K + k0 + scol,
                        Alds + chunk * 512);
        }
        if (F32) {
#pragma unroll
            for (int c = 0; c < 4; ++c) {
                int chunk = wave * 4 + c;
                int row   = chunk * 8 + sr;
                const float* gp = (const float*)W + (size_t)(nbase + row) * K + k0 + scol;
                float4v f0 = *(const float4v*)gp;
                float4v f1 = *(const float4v*)(gp + 4);
                short8 v;
#pragma unroll
                for (int j = 0; j < 4; ++j) v[j]     = (short)f32_to_bf16(f0[j]);
#pragma unroll
                for (int j = 0; j < 4; ++j) v[4 + j] = (short)f32_to_bf16(f1[j]);
                *(short8*)(Blds + chunk * 512 + lane * 8) = v;
            }
        } else {
#pragma unroll
            for (int c = 0; c < 4; ++c) {
                int chunk = wave * 4 + c;
                int row   = chunk * 8 + sr;
                gload_lds16((const ushort_t*)W + (size_t)(nbase + row) * K + k0 + scol,
                            Blds + chunk * 512);
            }
        }
        __syncthreads();

        short8 af[4][2], bf[4][2];
#pragma unroll
        for (int mi = 0; mi < 4; ++mi) {
            int row = wm + mi * 16 + l16;
#pragma unroll
            for (int kk = 0; kk < 2; ++kk) {
                int cb = (kk * 64 + l4 * 16) ^ ((l16 & 7) << 4);
                af[mi][kk] = *(const short8*)((const char*)Alds + row * 128 + cb);
            }
        }
#pragma unroll
        for (int ni = 0; ni < 4; ++ni) {
            int row = wn + ni * 16 + l16;
#pragma unroll
            for (int kk = 0; kk < 2; ++kk) {
                int cb = (kk * 64 + l4 * 16) ^ ((l16 & 7) << 4);
                bf[ni][kk] = *(const short8*)((const char*)Blds + row * 128 + cb);
            }
        }
#pragma unroll
        for (int mi = 0; mi < 4; ++mi)
#pragma unroll
            for (int ni = 0; ni < 4; ++ni) {
                acc[mi][ni] = __builtin_amdgcn_mfma_f32_16x16x32_bf16(
                    af[mi][0], bf[ni][0], acc[mi][ni], 0, 0, 0);
                acc[mi][ni] = __builtin_amdgcn_mfma_f32_16x16x32_bf16(
                    af[mi][1], bf[ni][1], acc[mi][ni], 0, 0, 0);
            }
    }

#pragma unroll
    for (int mi = 0; mi < 4; ++mi) {
#pragma unroll
        for (int ni = 0; ni < 4; ++ni) {
            int n = nbase + wn + ni * 16 + l16;
            float bv = load_bias(bias, n, F32);
#pragma unroll
            for (int r = 0; r < 4; ++r) {
                int m = mbase + wm + mi * 16 + l4 * 4 + r;
                if (m < M) {
                    float v = acc[mi][ni][r] + bv;
                    if (SMODE == 0) {
                        ((float*)C)[(size_t)m * N + n] = v;
                    } else {
                        size_t idx = (size_t)(BSZ + m) * N + n;
                        if (F32) ((float*)C)[idx] = v;
                        else     ((ushort_t*)C)[idx] = f32_to_bf16(v);
                    }
                }
            }
        }
    }
}

// ---------------------------------------------------------------------------
// PERSISTENT LSTM layer (same decomposition as round 2 — verified correct).
// Cross-WG sync: hand-rolled monotonic-counter barrier instead of cg
// grid.sync. Release: __syncthreads drains each wave's stores to L2
// (compiler emits vmcnt(0) before s_barrier), then tid0's RELEASE
// fetch_add performs the L2 writeback. Acquire: tid0 polls with ACQUIRE
// loads (buffer_inv covers this CU's L1 + XCD L2; all WG threads share
// that L1), then __syncthreads orders consumers behind it.
// ---------------------------------------------------------------------------
__device__ inline void lstm_grid_barrier(uint32_t* cnt, uint32_t target) {
    __syncthreads();
    if (threadIdx.x == 0) {
        __hip_atomic_fetch_add(cnt, 1u, __ATOMIC_RELEASE, __HIP_MEMORY_SCOPE_AGENT);
        while (__hip_atomic_load(cnt, __ATOMIC_ACQUIRE, __HIP_MEMORY_SCOPE_AGENT) < target)
            __builtin_amdgcn_s_sleep(2);
    }
    __syncthreads();
}

__global__ __launch_bounds__(256, 1)
void lstm_layer_kernel(const float* __restrict__ xih,   // (T,32,2048) fp32
                       ushort_t* __restrict__ hbuf,     // 2 x (32,512) bf16
                       float*    __restrict__ cbuf,     // (32,512) fp32
                       const void* __restrict__ Whh,    // (2048,512) bf16|fp32
                       ushort_t* __restrict__ ys,       // (T,32,512) bf16 | null
                       const ushort_t* __restrict__ probe,
                       int T,
                       uint32_t* __restrict__ bar_cnt)  // zeroed before launch
{
    const int F32 = detect_f32(probe);

    __shared__ ushort_t w_lds[32 * 512];   // 32 KB
    __shared__ ushort_t h_lds[32 * 512];   // 32 KB

    const int tid  = threadIdx.x;
    const int lane = tid & 63;
    const int wave = tid >> 6;
    const int l16  = lane & 15;
    const int quad = lane >> 4;
    const int j0   = blockIdx.x * 8;

    const int m0 = (wave >> 1) * 16;        // batch half
    const int ni = wave & 1;                // unit-quad select

    // ---- stage Whh slice once (rows rr = u8*4+gate)
#pragma unroll
    for (int i = 0; i < 8; ++i) {
        int idx = tid + i * 256;            // 0..2047 16B-chunks
        int rr  = idx >> 6;
        int c16 = idx & 63;
        int gate = rr & 3, u8 = rr >> 2;
        size_t grow = (size_t)(gate * HID + j0 + u8) * HID + c16 * 8;
        short8 v;
        if (F32) {
            const float* gp = (const float*)Whh + grow;
            float4v f0 = *(const float4v*)gp;
            float4v f1 = *(const float4v*)(gp + 4);
#pragma unroll
            for (int j = 0; j < 4; ++j) v[j]     = (short)f32_to_bf16(f0[j]);
#pragma unroll
            for (int j = 0; j < 4; ++j) v[4 + j] = (short)f32_to_bf16(f1[j]);
        } else {
            v = *(const short8*)((const ushort_t*)Whh + grow);
        }
        *(short8*)((char*)w_lds + rr * 1024 + ((c16 * 16) ^ ((rr & 7) << 4))) = v;
    }

    // ---- lane's (unit, gate) identity in the MFMA output tile
    const int u8me = ni * 4 + (l16 >> 2);
    const int gme  = l16 & 3;
    const int jme  = j0 + u8me;

    // cell state in registers (maintained by gate-0 lanes)
    float creg[4];
#pragma unroll
    for (int r = 0; r < 4; ++r)
        creg[r] = cbuf[(m0 + quad * 4 + r) * HID + jme];

    const bool has_ys = (ys != nullptr);

    for (int t = 0; t < T; ++t) {
        const ushort_t* hin  = hbuf + (size_t)(t & 1) * (BSZ * HID);
        ushort_t*       hout = hbuf + (size_t)((t + 1) & 1) * (BSZ * HID);
        const float*    xr   = xih + (size_t)t * (BSZ * FOURH);

        // prefetch this step's xih slice
        float xv[4];
#pragma unroll
        for (int r = 0; r < 4; ++r)
            xv[r] = xr[(m0 + quad * 4 + r) * FOURH + gme * HID + jme];

        // stage h -> LDS (swizzled)
#pragma unroll
        for (int i = 0; i < 8; ++i) {
            int idx = tid + i * 256;
            int b   = idx >> 6;
            int c16 = idx & 63;
            short8 v = *(const short8*)(hin + (size_t)b * HID + c16 * 8);
            *(short8*)((char*)h_lds + b * 1024 + ((c16 * 16) ^ ((b & 7) << 4))) = v;
        }
        __syncthreads();

        // MFMA: 16x16 output tile per wave (batch-half x row-half), K=512
        float4v acc = (float4v){0.f, 0.f, 0.f, 0.f};
#pragma unroll
        for (int kk = 0; kk < 16; ++kk) {
            int cb = (kk * 64 + quad * 16) ^ ((l16 & 7) << 4);
            short8 a = *(const short8*)((const char*)h_lds + (m0 + l16) * 1024 + cb);
            short8 b = *(const short8*)((const char*)w_lds + (ni * 16 + l16) * 1024 + cb);
            acc = __builtin_amdgcn_mfma_f32_16x16x32_bf16(a, b, acc, 0, 0, 0);
        }

        // gates: activation first (uniform single expf), then gather via shfl
#pragma unroll
        for (int r = 0; r < 4; ++r) {
            float g   = acc[r] + xv[r];
            float arg = (gme == 2) ? 2.f * g : g;
            float s   = 1.f / (1.f + expf(-arg));
            float act = (gme == 2) ? 2.f * s - 1.f : s;
            int base = lane & ~3;
            float ai = __shfl(act, base + 0);
            float af = __shfl(act, base + 1);
            float ag = __shfl(act, base + 2);
            float ao = __shfl(act, base + 3);
            if (gme == 0) {
                float cn = af * creg[r] + ai * ag;
                creg[r] = cn;
                float th = 2.f / (1.f + expf(-2.f * cn)) - 1.f;   // tanh(cn)
                float hn = ao * th;
                ushort_t hb = f32_to_bf16(hn);
                int b = m0 + quad * 4 + r;
                hout[b * HID + jme] = hb;
                if (has_ys) ys[(size_t)t * (BSZ * HID) + b * HID + jme] = hb;
            }
        }

        if (t != T - 1)
            lstm_grid_barrier(bar_cnt, (uint32_t)(t + 1) * NWG_LSTM);
        else
            __syncthreads();   // h_lds guard for... loop ends; keeps sym.
    }

    // final cell state (needed when a decoder layer continues this state)
    if (gme == 0) {
#pragma unroll
        for (int r = 0; r < 4; ++r)
            cbuf[(m0 + quad * 4 + r) * HID + jme] = creg[r];
    }
}

// ---------------------------------------------------------------------------
// Fallback per-step LSTM kernel (used only if cooperative launch fails).
// ---------------------------------------------------------------------------
__global__ void lstm_step_kernel(const float* __restrict__ xih,
                                 const ushort_t* __restrict__ h_in,
                                 ushort_t* __restrict__ h_out,
                                 float* __restrict__ c,
                                 const void* __restrict__ Whh,
                                 ushort_t* __restrict__ ys,
                                 const ushort_t* __restrict__ probe)
{
    const int F32 = detect_f32(probe);
    __shared__ uint32_t h_lds[BSZ * 257];
    __shared__ uint32_t w_lds[8 * 256];
    __shared__ float    g_lds[8][BSZ];

    const int tid = threadIdx.x;
    const int j0  = blockIdx.x * 2;

    const uint32_t* h32 = (const uint32_t*)h_in;
#pragma unroll
    for (int i = 0; i < 32; ++i) {
        int idx = tid + i * 256;
        int row = idx >> 8, col = idx & 255;
        h_lds[row * 257 + col] = h32[idx];
    }
#pragma unroll
    for (int i = 0; i < 8; ++i) {
        int idx  = tid + i * 256;
        int lrr  = idx >> 8, col = idx & 255;
        int gate = lrr >> 1, jl = lrr & 1;
        size_t wrow = (size_t)(gate * HID + j0 + jl);
        if (F32) {
            const float* wf = (const float*)Whh + wrow * HID + col * 2;
            uint32_t lo = f32_to_bf16(wf[0]);
            uint32_t hi = f32_to_bf16(wf[1]);
            w_lds[lrr * 256 + col] = lo | (hi << 16);
        } else {
            w_lds[lrr * 256 + col] = ((const uint32_t*)Whh)[wrow * 256 + col];
        }
    }
    __syncthreads();

    const int b    = tid & 31;
    const int lr   = tid >> 5;
    const int gate = lr >> 1;
    const int jl   = lr & 1;

    float dot = xih[b * FOURH + gate * HID + j0 + jl];
    const uint32_t* hr = &h_lds[b * 257];
    const uint32_t* wr = &w_lds[lr * 256];
    float s0 = 0.f, s1 = 0.f;
#pragma unroll 8
    for (int k = 0; k < 256; ++k) {
        uint32_t hu = hr[k], wu = wr[k];
        s0 += bf16lo(hu) * bf16lo(wu);
        s1 += bf16hi(hu) * bf16hi(wu);
    }
    g_lds[lr][b] = dot + s0 + s1;
    __syncthreads();

    if (tid < 64) {
        int b2 = tid & 31, jl2 = tid >> 5;
        int j  = j0 + jl2;
        float gi = g_lds[(0 << 1) | jl2][b2];
        float gf = g_lds[(1 << 1) | jl2][b2];
        float gg = g_lds[(2 << 1) | jl2][b2];
        float go = g_lds[(3 << 1) | jl2][b2];
        float cold = c[b2 * HID + j];
        float cn = sigmoid_f(gf) * cold + sigmoid_f(gi) * tanhf(gg);
        float hn = sigmoid_f(go) * tanhf(cn);
        c[b2 * HID + j] = cn;
        ushort_t hb = f32_to_bf16(hn);
        h_out[b2 * HID + j] = hb;
        if (ys) ys[b2 * HID + j] = hb;
    }
}

// ---------------------------------------------------------------------------
// Zero the first output timestep (elements [0, 32*VOC)), dtype per mode.
// ---------------------------------------------------------------------------
__global__ void zero_row_kernel(void* __restrict__ outv,
                                const ushort_t* __restrict__ probe)
{
    const int F32 = detect_f32(probe);
    int i = blockIdx.x * 256 + threadIdx.x;
    if (i >= BSZ * VOC) return;
    if (F32) ((uint32_t*)outv)[i] = 0u;
    else     ((ushort_t*)outv)[i] = 0;
}

// ---------------------------------------------------------------------------
// Scratch layout inside d_out (unchanged):
//   dy1 (bf16) at byte 0; arena at 4 MiB; arena (incl. barrier counters)
//   dead before projection overwrites it.
// ---------------------------------------------------------------------------
extern "C" void kernel_launch(void* const* d_in, const int* in_sizes, int n_in,
                              void* d_out, int out_size, void* d_ws, size_t ws_size,
                              hipStream_t stream)
{
    const int*      src      = (const int*)d_in[0];
    const int*      trg      = (const int*)d_in[1];
    const void*     enc_emb  = d_in[2];
    const void*     enc_Wih0 = d_in[3];
    const void*     enc_Whh0 = d_in[4];
    const void*     enc_b0   = d_in[5];
    const void*     enc_Wih1 = d_in[6];
    const void*     enc_Whh1 = d_in[7];
    const void*     enc_b1   = d_in[8];
    const void*     dec_emb  = d_in[9];
    const void*     dec_Wih0 = d_in[10];
    const void*     dec_Whh0 = d_in[11];
    const void*     dec_b0   = d_in[12];
    const void*     dec_Wih1 = d_in[13];
    const void*     dec_Whh1 = d_in[14];
    const void*     dec_b1   = d_in[15];
    const void*     out_W    = d_in[16];
    const void*     out_b    = d_in[17];

    const ushort_t* probe = (const ushort_t*)enc_b0;

    const int ME = SLEN * BSZ;   // 1600
    const int MD = TDEC * BSZ;   // 1248

    ushort_t* dy1 = (ushort_t*)d_out;

    char*  arena = (char*)d_out + (4u << 20);
    size_t aoff  = 0;
    auto acarve = [&](size_t bytes) -> void* {
        void* p = arena + aoff;
        aoff = (aoff + bytes + 255) & ~(size_t)255;
        return p;
    };
    const size_t HSTATE = (size_t)BSZ * HID;                       // 16384 elems
    float*    Xbig = (float*)acarve((size_t)ME * FOURH * 4);       // 13.1 MB
    ushort_t* X0   = (ushort_t*)acarve((size_t)ME * EMB * 2);
    ushort_t* DX0  = (ushort_t*)acarve((size_t)MD * EMB * 2);
    ushort_t* ys0  = (ushort_t*)acarve((size_t)ME * HID * 2);
    ushort_t* dy0  = (ushort_t*)acarve((size_t)MD * HID * 2);
    ushort_t* h0b  = (ushort_t*)acarve(2 * HSTATE * 2);
    float*    c0b  = (float*)acarve(HSTATE * 4);
    ushort_t* h1b  = (ushort_t*)acarve(2 * HSTATE * 2);
    float*    c1b  = (float*)acarve(HSTATE * 4);
    uint32_t* bars = (uint32_t*)acarve(4 * 256);    // 4 barrier counters, 256B apart

    hipMemsetAsync(h0b, 0, HSTATE * 2, stream);
    hipMemsetAsync(c0b, 0, HSTATE * 4, stream);
    hipMemsetAsync(h1b, 0, HSTATE * 2, stream);
    hipMemsetAsync(c1b, 0, HSTATE * 4, stream);
    hipMemsetAsync(bars, 0, 4 * 256, stream);

    {
        int tu = ME * (EMB / 2);
        embed_kernel<<<(tu + 255) / 256, 256, 0, stream>>>(
            src, enc_emb, (uint32_t*)X0, tu, probe);
        int td = MD * (EMB / 2);
        embed_kernel<<<(td + 255) / 256, 256, 0, stream>>>(
            trg, dec_emb, (uint32_t*)DX0, td, probe);
    }

    const size_t XIH_T = (size_t)BSZ * FOURH;
    const int MTE = (ME + 127) / 128;
    const int MTD = (MD + 127) / 128;

    // persistent LSTM layer launcher (cooperative; per-step fallback on error)
    auto launch_lstm = [&](const float* xih, ushort_t* hb, float* cb,
                           const void* Whh, ushort_t* ysp, int T, int layer) {
        const float* a0 = xih; ushort_t* a1 = hb; float* a2 = cb;
        const void* a3 = Whh; ushort_t* a4 = ysp;
        const ushort_t* a5 = probe; int a6 = T;
        uint32_t* a7 = bars + layer * 64;        // 256B-spaced counter
        void* ka[] = {(void*)&a0, (void*)&a1, (void*)&a2, (void*)&a3,
                      (void*)&a4, (void*)&a5, (void*)&a6, (void*)&a7};
        hipError_t e = hipLaunchCooperativeKernel(
            reinterpret_cast<const void*>(&lstm_layer_kernel),
            dim3(NWG_LSTM), dim3(256), ka, 0, stream);
        if (e != hipSuccess) {
            for (int t = 0; t < T; ++t)
                lstm_step_kernel<<<256, 256, 0, stream>>>(
                    xih + (size_t)t * XIH_T,
                    hb + (t & 1) * HSTATE, hb + ((t + 1) & 1) * HSTATE,
                    cb, Whh,
                    ysp ? ysp + (size_t)t * HSTATE : (ushort_t*)nullptr,
                    probe);
        }
    };

    // encoder layer 0
    gemm_tile_kernel<0><<<dim3(MTE, FOURH / 128), 256, 0, stream>>>(
        X0, enc_Wih0, enc_b0, Xbig, ME, FOURH, EMB, probe);
    launch_lstm(Xbig, h0b, c0b, enc_Whh0, ys0, SLEN, 0);

    // encoder layer 1 (only final state needed)
    gemm_tile_kernel<0><<<dim3(MTE, FOURH / 128), 256, 0, stream>>>(
        ys0, enc_Wih1, enc_b1, Xbig, ME, FOURH, HID, probe);
    launch_lstm(Xbig, h1b, c1b, enc_Whh1, (ushort_t*)nullptr, SLEN, 1);
    // 50 steps (even): final h at parity 0 -> decoder t=0 reads parity 0.

    // decoder layer 0 (continues h0b/c0b)
    gemm_tile_kernel<0><<<dim3(MTD, FOURH / 128), 256, 0, stream>>>(
        DX0, dec_Wih0, dec_b0, Xbig, MD, FOURH, EMB, probe);
    launch_lstm(Xbig, h0b, c0b, dec_Whh0, dy0, TDEC, 2);

    // decoder layer 1 (continues h1b/c1b)
    gemm_tile_kernel<0><<<dim3(MTD, FOURH / 128), 256, 0, stream>>>(
        dy0, dec_Wih1, dec_b1, Xbig, MD, FOURH, HID, probe);
    launch_lstm(Xbig, h1b, c1b, dec_Whh1, dy1, TDEC, 3);

    // projection: reads dy1 + out_W/out_b; writes [32*VOC, 1280*VOC) of d_out
    gemm_tile_kernel<1><<<dim3(MTD, VOC / 128), 256, 0, stream>>>(
        dy1, out_W, out_b, d_out, MD, VOC, HID, probe);

    // zero first output timestep — also wipes dy1
    zero_row_kernel<<<(BSZ * VOC + 255) / 256, 256, 0, stream>>>(d_out, probe);
}

// Round 4
// 1762.755 us; speedup vs baseline: 2.4048x; 1.0315x over previous
//
#include <hip/hip_runtime.h>
#include <hip/hip_bf16.h>
#include <stdint.h>

typedef unsigned short ushort_t;

#define HID 512
#define FOURH 2048
#define BSZ 32
#define SLEN 50
#define TDEC 39
#define EMB 256
#define VOC 32000
#define NWG_LSTM 64

using short8  = __attribute__((ext_vector_type(8))) short;
using float4v = __attribute__((ext_vector_type(4))) float;
using uint4v  = __attribute__((ext_vector_type(4))) unsigned int;

__device__ inline float bf16lo(uint32_t u) { return __uint_as_float(u << 16); }
__device__ inline float bf16hi(uint32_t u) { return __uint_as_float(u & 0xffff0000u); }

__device__ inline ushort_t f32_to_bf16(float f) {
    uint32_t u = __float_as_uint(f);
    uint32_t r = (u + 0x7fffu + ((u >> 16) & 1u)) >> 16;
    return (ushort_t)r;
}

__device__ inline float sigmoid_f(float x) { return 1.0f / (1.0f + expf(-x)); }

// ---------------------------------------------------------------------------
// Runtime dtype detection. Probe = enc_b0 (values ~N(0,1)*0.05).
// Returns 1 if inputs are fp32 (wave-uniform).
// ---------------------------------------------------------------------------
__device__ inline int detect_f32(const ushort_t* __restrict__ probe) {
    int cnt = 0;
#pragma unroll
    for (int i = 0; i < 64; ++i) {
        int e = (probe[i] >> 7) & 0xFF;
        cnt += (e >= 0x8A);
    }
    return cnt > 0;
}

// ---------------------------------------------------------------------------
// Embedding gather -> bf16 pairs. Handles bf16 or fp32 source table.
// ---------------------------------------------------------------------------
__global__ void embed_kernel(const int* __restrict__ idx,
                             const void* __restrict__ emb,
                             uint32_t* __restrict__ out,
                             int total_u,
                             const ushort_t* __restrict__ probe)
{
    const int F32 = detect_f32(probe);
    int i = blockIdx.x * 256 + threadIdx.x;
    if (i >= total_u) return;
    int tok = i >> 7;          // EMB/2 = 128 uints per row
    int col = i & 127;
    int row = idx[tok];
    if (F32) {
        const float* ef = (const float*)emb + (size_t)row * EMB + col * 2;
        uint32_t lo = f32_to_bf16(ef[0]);
        uint32_t hi = f32_to_bf16(ef[1]);
        out[i] = lo | (hi << 16);
    } else {
        out[i] = ((const uint32_t*)emb)[(size_t)row * 128 + col];
    }
}

__device__ inline float load_bias(const void* __restrict__ bias, int n, int F32) {
    if (F32) return ((const float*)bias)[n];
    return __uint_as_float(((uint32_t)((const ushort_t*)bias)[n]) << 16);
}

__device__ inline void gload_lds16(const ushort_t* __restrict__ g, ushort_t* l) {
    __builtin_amdgcn_global_load_lds(
        (const __attribute__((address_space(1))) uint32_t*)g,
        (__attribute__((address_space(3))) uint32_t*)l,
        16, 0, 0);
}

// ---------------------------------------------------------------------------
// Tiled GEMM: C[M,N] = A[M,K](bf16 internal) @ W[N,K](bf16|fp32)^T + bias
// 128x128 tile, BK=64, 4 waves (2x2), XOR-swizzled LDS (see round-1 notes).
// SMODE 0: C = float* scratch; SMODE 1: C = d_out, idx=(32+m)*N+n.
// ---------------------------------------------------------------------------
template <int SMODE>
__global__ __launch_bounds__(256, 3)
void gemm_tile_kernel(const ushort_t* __restrict__ A,
                      const void* __restrict__ W,
                      const void* __restrict__ bias,
                      void* __restrict__ C,
                      int M, int N, int K,
                      const ushort_t* __restrict__ probe)
{
    const int F32 = detect_f32(probe);
    __shared__ ushort_t Alds[128 * 64];   // 16 KB
    __shared__ ushort_t Blds[128 * 64];   // 16 KB

    const int tid  = threadIdx.x;
    const int lane = tid & 63;
    const int wave = tid >> 6;
    const int l16  = lane & 15;
    const int l4   = lane >> 4;

    const int wm = (wave >> 1) * 64;
    const int wn = (wave & 1) * 64;

    const int mbase = blockIdx.x * 128;
    const int nbase = blockIdx.y * 128;

    const int sr   = lane >> 3;                   // sub-row 0..7
    const int scol = ((lane & 7) ^ sr) * 8;       // swizzled source col (elems)

    float4v acc[4][4];
#pragma unroll
    for (int i = 0; i < 4; ++i)
#pragma unroll
        for (int j = 0; j < 4; ++j) acc[i][j] = (float4v){0.f, 0.f, 0.f, 0.f};

    for (int k0 = 0; k0 < K; k0 += 64) {
        __syncthreads();

#pragma unroll
        for (int c = 0; c < 4; ++c) {
            int chunk = wave * 4 + c;
            int row   = chunk * 8 + sr;
            gload_lds16(A + (size_t)(mbase + row) * K + k0 + scol,
                        Alds + chunk * 512);
        }
        if (F32) {
#pragma unroll
            for (int c = 0; c < 4; ++c) {
                int chunk = wave * 4 + c;
                int row   = chunk * 8 + sr;
                const float* gp = (const float*)W + (size_t)(nbase + row) * K + k0 + scol;
                float4v f0 = *(const float4v*)gp;
                float4v f1 = *(const float4v*)(gp + 4);
                short8 v;
#pragma unroll
                for (int j = 0; j < 4; ++j) v[j]     = (short)f32_to_bf16(f0[j]);
#pragma unroll
                for (int j = 0; j < 4; ++j) v[4 + j] = (short)f32_to_bf16(f1[j]);
                *(short8*)(Blds + chunk * 512 + lane * 8) = v;
            }
        } else {
#pragma unroll
            for (int c = 0; c < 4; ++c) {
                int chunk = wave * 4 + c;
                int row   = chunk * 8 + sr;
                gload_lds16((const ushort_t*)W + (size_t)(nbase + row) * K + k0 + scol,
                            Blds + chunk * 512);
            }
        }
        __syncthreads();

        short8 af[4][2], bf[4][2];
#pragma unroll
        for (int mi = 0; mi < 4; ++mi) {
            int row = wm + mi * 16 + l16;
#pragma unroll
            for (int kk = 0; kk < 2; ++kk) {
                int cb = (kk * 64 + l4 * 16) ^ ((l16 & 7) << 4);
                af[mi][kk] = *(const short8*)((const char*)Alds + row * 128 + cb);
            }
        }
#pragma unroll
        for (int ni = 0; ni < 4; ++ni) {
            int row = wn + ni * 16 + l16;
#pragma unroll
            for (int kk = 0; kk < 2; ++kk) {
                int cb = (kk * 64 + l4 * 16) ^ ((l16 & 7) << 4);
                bf[ni][kk] = *(const short8*)((const char*)Blds + row * 128 + cb);
            }
        }
#pragma unroll
        for (int mi = 0; mi < 4; ++mi)
#pragma unroll
            for (int ni = 0; ni < 4; ++ni) {
                acc[mi][ni] = __builtin_amdgcn_mfma_f32_16x16x32_bf16(
                    af[mi][0], bf[ni][0], acc[mi][ni], 0, 0, 0);
                acc[mi][ni] = __builtin_amdgcn_mfma_f32_16x16x32_bf16(
                    af[mi][1], bf[ni][1], acc[mi][ni], 0, 0, 0);
            }
    }

#pragma unroll
    for (int mi = 0; mi < 4; ++mi) {
#pragma unroll
        for (int ni = 0; ni < 4; ++ni) {
            int n = nbase + wn + ni * 16 + l16;
            float bv = load_bias(bias, n, F32);
#pragma unroll
            for (int r = 0; r < 4; ++r) {
                int m = mbase + wm + mi * 16 + l4 * 4 + r;
                if (m < M) {
                    float v = acc[mi][ni][r] + bv;
                    if (SMODE == 0) {
                        ((float*)C)[(size_t)m * N + n] = v;
                    } else {
                        size_t idx = (size_t)(BSZ + m) * N + n;
                        if (F32) ((float*)C)[idx] = v;
                        else     ((ushort_t*)C)[idx] = f32_to_bf16(v);
                    }
                }
            }
        }
    }
}

// ---------------------------------------------------------------------------
// PERSISTENT LSTM layer, fence-free cross-WG protocol:
//  - h is exchanged via RELAXED AGENT-scope atomics (sc1 accesses: per-access
//    coherent through the LLC, bypassing the non-coherent per-XCD L2). No
//    buffer_wbl2 / buffer_inv is ever executed.
//  - barrier: explicit per-wave s_waitcnt vmcnt(0) (h stores ack'd at the
//    coherence point) -> __syncthreads -> tid0 RELAXED fetch_add + RELAXED
//    poll -> __syncthreads. Pure control sync, no cache maintenance.
//  - Whh fragments live in registers (16 x short8, loop-invariant).
// ---------------------------------------------------------------------------
__device__ inline void lstm_grid_barrier(uint32_t* cnt, uint32_t target) {
    asm volatile("s_waitcnt vmcnt(0)" ::: "memory");  // own wave's h stores at LLC
    __syncthreads();                                  // all waves arrived (each drained)
    if (threadIdx.x == 0) {
        __hip_atomic_fetch_add(cnt, 1u, __ATOMIC_RELAXED, __HIP_MEMORY_SCOPE_AGENT);
        while (__hip_atomic_load(cnt, __ATOMIC_RELAXED, __HIP_MEMORY_SCOPE_AGENT) < target)
            __builtin_amdgcn_s_sleep(1);
    }
    __syncthreads();
}

__global__ __launch_bounds__(256, 1)
void lstm_layer_kernel(const float* __restrict__ xih,   // (T,32,2048) fp32
                       ushort_t* __restrict__ hbuf,     // 2 x (32,512) bf16
                       float*    __restrict__ cbuf,     // (32,512) fp32
                       const void* __restrict__ Whh,    // (2048,512) bf16|fp32
                       ushort_t* __restrict__ ys,       // (T,32,512) bf16 | null
                       const ushort_t* __restrict__ probe,
                       int T,
                       uint32_t* __restrict__ bar_cnt)  // zeroed before launch
{
    const int F32 = detect_f32(probe);

    __shared__ ushort_t h_lds[32 * 512];   // 32 KB (XOR-swizzled rows)

    const int tid  = threadIdx.x;
    const int lane = tid & 63;
    const int wave = tid >> 6;
    const int l16  = lane & 15;
    const int quad = lane >> 4;
    const int j0   = blockIdx.x * 8;

    const int m0 = (wave >> 1) * 16;        // batch half
    const int ni = wave & 1;                // unit-quad select

    // ---- lane's (unit, gate) identity in the MFMA output tile
    const int u8me = ni * 4 + (l16 >> 2);
    const int gme  = l16 & 3;
    const int jme  = j0 + u8me;

    // ---- Whh B-fragments -> registers (loop-invariant). Lane supplies the
    // B row rr = ni*16+l16 (gate = l16&3, u8 = u8me), cols kk*32+quad*8.
    short8 wfrag[16];
    {
        const size_t grow = (size_t)(gme * HID + j0 + u8me) * HID;
#pragma unroll
        for (int kk = 0; kk < 16; ++kk) {
            size_t off = grow + kk * 32 + quad * 8;
            if (F32) {
                const float* gp = (const float*)Whh + off;
                float4v f0 = *(const float4v*)gp;
                float4v f1 = *(const float4v*)(gp + 4);
                short8 v;
#pragma unroll
                for (int j = 0; j < 4; ++j) v[j]     = (short)f32_to_bf16(f0[j]);
#pragma unroll
                for (int j = 0; j < 4; ++j) v[4 + j] = (short)f32_to_bf16(f1[j]);
                wfrag[kk] = v;
            } else {
                wfrag[kk] = *(const short8*)((const ushort_t*)Whh + off);
            }
        }
    }

    // cell state in registers. Lanes l16 = 4q..4q+3 share u8me -> identical
    // creg across each 4-lane group; all lanes run the update redundantly.
    float creg[4];
#pragma unroll
    for (int r = 0; r < 4; ++r)
        creg[r] = cbuf[(m0 + quad * 4 + r) * HID + jme];

    const bool has_ys = (ys != nullptr);
    uint32_t* ys32 = (uint32_t*)ys;

    for (int t = 0; t < T; ++t) {
        const uint32_t* h32in =
            (const uint32_t*)(hbuf + (size_t)(t & 1) * (BSZ * HID));
        uint32_t* h32out =
            (uint32_t*)(hbuf + (size_t)((t + 1) & 1) * (BSZ * HID));
        const float* xr = xih + (size_t)t * (BSZ * FOURH);

        // prefetch this step's xih slice (plain; read-only, pre-written)
        float xv[4];
#pragma unroll
        for (int r = 0; r < 4; ++r)
            xv[r] = xr[(m0 + quad * 4 + r) * FOURH + gme * HID + jme];

        // stage h -> LDS (swizzled). Reads are relaxed agent atomics (sc1,
        // LLC-coherent) -> no cache invalidation needed anywhere.
#pragma unroll
        for (int i = 0; i < 8; ++i) {
            int idx = tid + i * 256;          // 16B-chunk id 0..2047
            int b   = idx >> 6;
            int c16 = idx & 63;
            const uint32_t* gp = h32in + b * 256 + c16 * 4;
            uint4v dv;
            dv[0] = __hip_atomic_load(gp + 0, __ATOMIC_RELAXED, __HIP_MEMORY_SCOPE_AGENT);
            dv[1] = __hip_atomic_load(gp + 1, __ATOMIC_RELAXED, __HIP_MEMORY_SCOPE_AGENT);
            dv[2] = __hip_atomic_load(gp + 2, __ATOMIC_RELAXED, __HIP_MEMORY_SCOPE_AGENT);
            dv[3] = __hip_atomic_load(gp + 3, __ATOMIC_RELAXED, __HIP_MEMORY_SCOPE_AGENT);
            *(uint4v*)((char*)h_lds + b * 1024 + ((c16 * 16) ^ ((b & 7) << 4))) = dv;
        }
        __syncthreads();

        // MFMA: 16x16 output tile per wave (batch-half x row-half), K=512
        float4v acc = (float4v){0.f, 0.f, 0.f, 0.f};
#pragma unroll
        for (int kk = 0; kk < 16; ++kk) {
            int cb = (kk * 64 + quad * 16) ^ ((l16 & 7) << 4);
            short8 a = *(const short8*)((const char*)h_lds + (m0 + l16) * 1024 + cb);
            acc = __builtin_amdgcn_mfma_f32_16x16x32_bf16(a, wfrag[kk], acc, 0, 0, 0);
        }

        // gates: all lanes compute the full update redundantly (consistent
        // within each 4-lane group); lanes l16 in {0,8} store packed dwords.
#pragma unroll
        for (int r = 0; r < 4; ++r) {
            float g   = acc[r] + xv[r];
            float arg = (gme == 2) ? 2.f * g : g;
            float s   = 1.f / (1.f + expf(-arg));
            float act = (gme == 2) ? 2.f * s - 1.f : s;
            int base = lane & ~3;
            float ai = __shfl(act, base + 0);
            float af = __shfl(act, base + 1);
            float ag = __shfl(act, base + 2);
            float ao = __shfl(act, base + 3);
            float cn = af * creg[r] + ai * ag;
            creg[r] = cn;
            float th = 2.f / (1.f + expf(-2.f * cn)) - 1.f;   // tanh(cn)
            float hn = ao * th;
            ushort_t hb = f32_to_bf16(hn);
            uint32_t dw = (uint32_t)hb |
                          ((uint32_t)(ushort_t)__shfl((int)hb, (lane + 4) & 63) << 16);
            if ((l16 & 7) == 0) {             // u8me even -> owns dword jme/2
                int b = m0 + quad * 4 + r;
                int di = b * 256 + ((j0 + u8me) >> 1);
                __hip_atomic_store(h32out + di, dw,
                                   __ATOMIC_RELAXED, __HIP_MEMORY_SCOPE_AGENT);
                if (has_ys) ys32[(size_t)t * 8192 + di] = dw;
            }
        }

        if (t != T - 1)
            lstm_grid_barrier(bar_cnt, (uint32_t)(t + 1) * NWG_LSTM);
    }

    // final cell state (one lane per 4-lane group)
    if (gme == 0) {
#pragma unroll
        for (int r = 0; r < 4; ++r)
            cbuf[(m0 + quad * 4 + r) * HID + jme] = creg[r];
    }
}

// ---------------------------------------------------------------------------
// Fallback per-step LSTM kernel (used only if cooperative launch fails).
// ---------------------------------------------------------------------------
__global__ void lstm_step_kernel(const float* __restrict__ xih,
                                 const ushort_t* __restrict__ h_in,
                                 ushort_t* __restrict__ h_out,
                                 float* __restrict__ c,
                                 const void* __restrict__ Whh,
                                 ushort_t* __restrict__ ys,
                                 const ushort_t* __restrict__ probe)
{
    const int F32 = detect_f32(probe);
    __shared__ uint32_t h_lds[BSZ * 257];
    __shared__ uint32_t w_lds[8 * 256];
    __shared__ float    g_lds[8][BSZ];

    const int tid = threadIdx.x;
    const int j0  = blockIdx.x * 2;

    const uint32_t* h32 = (const uint32_t*)h_in;
#pragma unroll
    for (int i = 0; i < 32; ++i) {
        int idx = tid + i * 256;
        int row = idx >> 8, col = idx & 255;
        h_lds[row * 257 + col] = h32[idx];
    }
#pragma unroll
    for (int i = 0; i < 8; ++i) {
        int idx  = tid + i * 256;
        int lrr  = idx >> 8, col = idx & 255;
        int gate = lrr >> 1, jl = lrr & 1;
        size_t wrow = (size_t)(gate * HID + j0 + jl);
        if (F32) {
            const float* wf = (const float*)Whh + wrow * HID + col * 2;
            uint32_t lo = f32_to_bf16(wf[0]);
            uint32_t hi = f32_to_bf16(wf[1]);
            w_lds[lrr * 256 + col] = lo | (hi << 16);
        } else {
            w_lds[lrr * 256 + col] = ((const uint32_t*)Whh)[wrow * 256 + col];
        }
    }
    __syncthreads();

    const int b    = tid & 31;
    const int lr   = tid >> 5;
    const int gate = lr >> 1;
    const int jl   = lr & 1;

    float dot = xih[b * FOURH + gate * HID + j0 + jl];
    const uint32_t* hr = &h_lds[b * 257];
    const uint32_t* wr = &w_lds[lr * 256];
    float s0 = 0.f, s1 = 0.f;
#pragma unroll 8
    for (int k = 0; k < 256; ++k) {
        uint32_t hu = hr[k], wu = wr[k];
        s0 += bf16lo(hu) * bf16lo(wu);
        s1 += bf16hi(hu) * bf16hi(wu);
    }
    g_lds[lr][b] = dot + s0 + s1;
    __syncthreads();

    if (tid < 64) {
        int b2 = tid & 31, jl2 = tid >> 5;
        int j  = j0 + jl2;
        float gi = g_lds[(0 << 1) | jl2][b2];
        float gf = g_lds[(1 << 1) | jl2][b2];
        float gg = g_lds[(2 << 1) | jl2][b2];
        float go = g_lds[(3 << 1) | jl2][b2];
        float cold = c[b2 * HID + j];
        float cn = sigmoid_f(gf) * cold + sigmoid_f(gi) * tanhf(gg);
        float hn = sigmoid_f(go) * tanhf(cn);
        c[b2 * HID + j] = cn;
        ushort_t hb = f32_to_bf16(hn);
        h_out[b2 * HID + j] = hb;
        if (ys) ys[b2 * HID + j] = hb;
    }
}

// ---------------------------------------------------------------------------
// Zero the first output timestep (elements [0, 32*VOC)), dtype per mode.
// ---------------------------------------------------------------------------
__global__ void zero_row_kernel(void* __restrict__ outv,
                                const ushort_t* __restrict__ probe)
{
    const int F32 = detect_f32(probe);
    int i = blockIdx.x * 256 + threadIdx.x;
    if (i >= BSZ * VOC) return;
    if (F32) ((uint32_t*)outv)[i] = 0u;
    else     ((ushort_t*)outv)[i] = 0;
}

// ---------------------------------------------------------------------------
// Scratch layout inside d_out (unchanged):
//   dy1 (bf16) at byte 0; arena at 4 MiB; arena (incl. barrier counters)
//   dead before projection overwrites it.
// ---------------------------------------------------------------------------
extern "C" void kernel_launch(void* const* d_in, const int* in_sizes, int n_in,
                              void* d_out, int out_size, void* d_ws, size_t ws_size,
                              hipStream_t stream)
{
    const int*      src      = (const int*)d_in[0];
    const int*      trg      = (const int*)d_in[1];
    const void*     enc_emb  = d_in[2];
    const void*     enc_Wih0 = d_in[3];
    const void*     enc_Whh0 = d_in[4];
    const void*     enc_b0   = d_in[5];
    const void*     enc_Wih1 = d_in[6];
    const void*     enc_Whh1 = d_in[7];
    const void*     enc_b1   = d_in[8];
    const void*     dec_emb  = d_in[9];
    const void*     dec_Wih0 = d_in[10];
    const void*     dec_Whh0 = d_in[11];
    const void*     dec_b0   = d_in[12];
    const void*     dec_Wih1 = d_in[13];
    const void*     dec_Whh1 = d_in[14];
    const void*     dec_b1   = d_in[15];
    const void*     out_W    = d_in[16];
    const void*     out_b    = d_in[17];

    const ushort_t* probe = (const ushort_t*)enc_b0;

    const int ME = SLEN * BSZ;   // 1600
    const int MD = TDEC * BSZ;   // 1248

    ushort_t* dy1 = (ushort_t*)d_out;

    char*  arena = (char*)d_out + (4u << 20);
    size_t aoff  = 0;
    auto acarve = [&](size_t bytes) -> void* {
        void* p = arena + aoff;
        aoff = (aoff + bytes + 255) & ~(size_t)255;
        return p;
    };
    const size_t HSTATE = (size_t)BSZ * HID;                       // 16384 elems
    float*    Xbig = (float*)acarve((size_t)ME * FOURH * 4);       // 13.1 MB
    ushort_t* X0   = (ushort_t*)acarve((size_t)ME * EMB * 2);
    ushort_t* DX0  = (ushort_t*)acarve((size_t)MD * EMB * 2);
    ushort_t* ys0  = (ushort_t*)acarve((size_t)ME * HID * 2);
    ushort_t* dy0  = (ushort_t*)acarve((size_t)MD * HID * 2);
    ushort_t* h0b  = (ushort_t*)acarve(2 * HSTATE * 2);
    float*    c0b  = (float*)acarve(HSTATE * 4);
    ushort_t* h1b  = (ushort_t*)acarve(2 * HSTATE * 2);
    float*    c1b  = (float*)acarve(HSTATE * 4);
    uint32_t* bars = (uint32_t*)acarve(4 * 256);    // 4 barrier counters, 256B apart

    hipMemsetAsync(h0b, 0, HSTATE * 2, stream);
    hipMemsetAsync(c0b, 0, HSTATE * 4, stream);
    hipMemsetAsync(h1b, 0, HSTATE * 2, stream);
    hipMemsetAsync(c1b, 0, HSTATE * 4, stream);
    hipMemsetAsync(bars, 0, 4 * 256, stream);

    {
        int tu = ME * (EMB / 2);
        embed_kernel<<<(tu + 255) / 256, 256, 0, stream>>>(
            src, enc_emb, (uint32_t*)X0, tu, probe);
        int td = MD * (EMB / 2);
        embed_kernel<<<(td + 255) / 256, 256, 0, stream>>>(
            trg, dec_emb, (uint32_t*)DX0, td, probe);
    }

    const size_t XIH_T = (size_t)BSZ * FOURH;
    const int MTE = (ME + 127) / 128;
    const int MTD = (MD + 127) / 128;

    // persistent LSTM layer launcher (cooperative; per-step fallback on error)
    auto launch_lstm = [&](const float* xih, ushort_t* hb, float* cb,
                           const void* Whh, ushort_t* ysp, int T, int layer) {
        const float* a0 = xih; ushort_t* a1 = hb; float* a2 = cb;
        const void* a3 = Whh; ushort_t* a4 = ysp;
        const ushort_t* a5 = probe; int a6 = T;
        uint32_t* a7 = bars + layer * 64;        // 256B-spaced counter
        void* ka[] = {(void*)&a0, (void*)&a1, (void*)&a2, (void*)&a3,
                      (void*)&a4, (void*)&a5, (void*)&a6, (void*)&a7};
        hipError_t e = hipLaunchCooperativeKernel(
            reinterpret_cast<const void*>(&lstm_layer_kernel),
            dim3(NWG_LSTM), dim3(256), ka, 0, stream);
        if (e != hipSuccess) {
            for (int t = 0; t < T; ++t)
                lstm_step_kernel<<<256, 256, 0, stream>>>(
                    xih + (size_t)t * XIH_T,
                    hb + (t & 1) * HSTATE, hb + ((t + 1) & 1) * HSTATE,
                    cb, Whh,
                    ysp ? ysp + (size_t)t * HSTATE : (ushort_t*)nullptr,
                    probe);
        }
    };

    // encoder layer 0
    gemm_tile_kernel<0><<<dim3(MTE, FOURH / 128), 256, 0, stream>>>(
        X0, enc_Wih0, enc_b0, Xbig, ME, FOURH, EMB, probe);
    launch_lstm(Xbig, h0b, c0b, enc_Whh0, ys0, SLEN, 0);

    // encoder layer 1 (only final state needed)
    gemm_tile_kernel<0><<<dim3(MTE, FOURH / 128), 256, 0, stream>>>(
        ys0, enc_Wih1, enc_b1, Xbig, ME, FOURH, HID, probe);
    launch_lstm(Xbig, h1b, c1b, enc_Whh1, (ushort_t*)nullptr, SLEN, 1);
    // 50 steps (even): final h at parity 0 -> decoder t=0 reads parity 0.

    // decoder layer 0 (continues h0b/c0b)
    gemm_tile_kernel<0><<<dim3(MTD, FOURH / 128), 256, 0, stream>>>(
        DX0, dec_Wih0, dec_b0, Xbig, MD, FOURH, EMB, probe);
    launch_lstm(Xbig, h0b, c0b, dec_Whh0, dy0, TDEC, 2);

    // decoder layer 1 (continues h1b/c1b)
    gemm_tile_kernel<0><<<dim3(MTD, FOURH / 128), 256, 0, stream>>>(
        dy0, dec_Wih1, dec_b1, Xbig, MD, FOURH, HID, probe);
    launch_lstm(Xbig, h1b, c1b, dec_Whh1, dy1, TDEC, 3);

    // projection: reads dy1 + out_W/out_b; writes [32*VOC, 1280*VOC) of d_out
    gemm_tile_kernel<1><<<dim3(MTD, VOC / 128), 256, 0, stream>>>(
        dy1, out_W, out_b, d_out, MD, VOC, HID, probe);

    // zero first output timestep — also wipes dy1
    zero_row_kernel<<<(BSZ * VOC + 255) / 256, 256, 0, stream>>>(d_out, probe);
}